// Round 15
// baseline (74.441 us; speedup 1.0000x reference)
//
#include <hip/hip_runtime.h>
#include <hip/hip_bf16.h>

typedef unsigned short ushort;
typedef __attribute__((ext_vector_type(8))) short bf16x8;     // MFMA A/B frag (8 bf16)
typedef __attribute__((ext_vector_type(8))) unsigned short ushort8;
typedef __attribute__((ext_vector_type(4))) float f32x4;      // MFMA C/D frag
typedef __attribute__((ext_vector_type(4))) float float4v;

__device__ __forceinline__ ushort f2bf(float f) {
    union { float f; unsigned u; } v; v.f = f;
    unsigned r = v.u + 0x7FFFu + ((v.u >> 16) & 1u);
    return (ushort)(r >> 16);
}
__device__ __forceinline__ float bf2f(ushort u) {
    union { unsigned u; float f; } v; v.u = ((unsigned)u) << 16;
    return v.f;
}

// Fragment-buffer geometry (ushort offsets; each frag = 64 lanes x 8 elems = 512)
//  Kf : (((qb*8 + h)*5 + f)*2 + kt)*512 + lane*8 + e   qb<5
//  Vf : (((vb*8 + h)*3 + f)*3 + kt)*512 + lane*8 + e   vb<5   (VPf: vb=p<3)
//  Wof/Wqf: ((kk*2 + half)*10 + f)*512 + lane*8 + e    kk<10, half<2, f<10
#define KF_SZ   (5u * 8 * 5 * 2 * 512)     //    204,800
#define VF_SZ   (5u * 8 * 3 * 3 * 512)     //    368,640
#define VPF_SZ  (3u * 8 * 3 * 3 * 512)     //    221,184
#define WF_SZ   (10u * 2 * 10 * 512)       //    102,400

// ---------------------------------------------------------------------------
// Weight transpose (blocks 0..679) + frag-buffer zero-fill (blocks 680..1068).
// ---------------------------------------------------------------------------
__global__ __launch_bounds__(256) void prep_k(
    const float* __restrict__ Wq, const float* __restrict__ Wk,
    const float* __restrict__ Wv, const float* __restrict__ Wo,
    ushort* __restrict__ Wq_t, ushort* __restrict__ Wk_t,
    ushort* __restrict__ Wv_t, ushort* __restrict__ Wo_t,
    ushort* __restrict__ Kf, ushort* __restrict__ Vf, ushort* __restrict__ VPf)
{
    int b = blockIdx.x;
    if (b >= 680) {         // zero-fill pads
        const ushort8 z8 = {0,0,0,0,0,0,0,0};
        unsigned i = (b - 680) * 256 + threadIdx.x;
        if (i < KF_SZ / 8) ((ushort8*)Kf)[i] = z8;
        else if (i < (KF_SZ + VF_SZ) / 8) ((ushort8*)Vf)[i - KF_SZ / 8] = z8;
        else if (i < (KF_SZ + VF_SZ + VPF_SZ) / 8) ((ushort8*)VPf)[i - (KF_SZ + VF_SZ) / 8] = z8;
        return;
    }
    __shared__ ushort t[32][33];
    const float* src; ushort* dst; int K; int tb;
    if (b < 100)      { src = Wq; dst = Wq_t; K = 320; tb = b; }
    else if (b < 340) { src = Wk; dst = Wk_t; K = 768; tb = b - 100; }
    else if (b < 580) { src = Wv; dst = Wv_t; K = 768; tb = b - 340; }
    else              { src = Wo; dst = Wo_t; K = 320; tb = b - 580; }
    int tc = tb % 10, tr = tb / 10;
    int tx = threadIdx.x & 31, ty = threadIdx.x >> 5;
    #pragma unroll
    for (int p = 0; p < 4; ++p) {
        int k = tr * 32 + ty + p * 8, n = tc * 32 + tx;
        t[ty + p * 8][tx] = f2bf(src[(size_t)k * 320 + n]);
    }
    __syncthreads();
    #pragma unroll
    for (int p = 0; p < 4; ++p) {
        int n = tc * 32 + ty + p * 8, k = tr * 32 + tx;
        dst[(size_t)n * K + k] = t[tx][ty + p * 8];
    }
}

// ---------------------------------------------------------------------------
// Split-K k/v projection partials (bid<160) + Wof/Wqf fragment formatters
// (bid 160..259; Wof first 12800 chunks, Wqf next 12800).
// ---------------------------------------------------------------------------
__global__ __launch_bounds__(256) void gemm_kv(
    const float* __restrict__ E, const ushort* __restrict__ Wk_t,
    const ushort* __restrict__ Wv_t, const ushort* __restrict__ Wq_t,
    const ushort* __restrict__ Wo_t,
    float* __restrict__ part, ushort* __restrict__ Wof, ushort* __restrict__ Wqf)
{
    const int tid = threadIdx.x;
    const int bid = blockIdx.x;
    if (bid >= 160) {       // fragment formatters
        int i = (bid - 160) * 256 + tid;
        const ushort* src; ushort* dst;
        if (i < 12800) { src = Wo_t; dst = Wof; }
        else           { src = Wq_t; dst = Wqf; i -= 12800; }
        int g = i >> 6, l = i & 63;
        int kk = g / 20, half = (g / 10) & 1, f = g % 10;
        int n = half * 160 + f * 16 + (l & 15);
        int k0 = kk * 32 + (l >> 4) * 8;
        *(ushort8*)(dst + (size_t)g * 512 + l * 8) =
            *(const ushort8*)(src + (size_t)n * 320 + k0);
        return;
    }
    __shared__ ushort A_lds[2][64 * 40];
    __shared__ ushort B_lds[2][320 * 40];
    const int w = tid >> 6, l = tid & 63;
    const int c15 = l & 15, khi = (l >> 4) * 8;
    const int r = tid >> 2, p = (tid & 3) * 8;
    const int rbase = (l >> 4) * 4;
    f32x4 acc[4][5] = {};

    const int mtile = bid % 10, mat = (bid / 10) & 1, ks = bid / 20;
    const int m0 = mtile * 64, kk0 = ks * 96;
    const ushort* Bt = mat ? Wv_t : Wk_t;
    const int m = m0 + r;
    const bool live = (m < 616);
    const float* Abase = E + (size_t)(live ? m : 0) * 768 + p;
    float4v a0 = {0,0,0,0}, a1 = {0,0,0,0};
    ushort8 breg[5];
    if (live) { a0 = *(const float4v*)(Abase + kk0); a1 = *(const float4v*)(Abase + kk0 + 4); }
    #pragma unroll
    for (int i = 0; i < 5; ++i) {
        int idx = tid + i * 256; int n = idx >> 2, q = (idx & 3) * 8;
        breg[i] = *(const ushort8*)(Bt + (size_t)n * 768 + kk0 + q);
    }
    {
        ushort* d = &A_lds[0][r * 40 + p];
        d[0]=f2bf(a0.x); d[1]=f2bf(a0.y); d[2]=f2bf(a0.z); d[3]=f2bf(a0.w);
        d[4]=f2bf(a1.x); d[5]=f2bf(a1.y); d[6]=f2bf(a1.z); d[7]=f2bf(a1.w);
        #pragma unroll
        for (int i = 0; i < 5; ++i) {
            int idx = tid + i * 256; int n = idx >> 2, q = (idx & 3) * 8;
            *(ushort8*)&B_lds[0][n * 40 + q] = breg[i];
        }
    }
    __syncthreads();
    for (int k = 0; k < 3; ++k) {
        const int cur = k & 1;
        if (k < 2) {
            int kk = kk0 + (k + 1) * 32;
            if (live) { a0 = *(const float4v*)(Abase + kk); a1 = *(const float4v*)(Abase + kk + 4); }
            #pragma unroll
            for (int i = 0; i < 5; ++i) {
                int idx = tid + i * 256; int n = idx >> 2, q = (idx & 3) * 8;
                breg[i] = *(const ushort8*)(Bt + (size_t)n * 768 + kk + q);
            }
        }
        bf16x8 a[4];
        #pragma unroll
        for (int mf = 0; mf < 4; ++mf)
            a[mf] = *(const bf16x8*)&A_lds[cur][(mf * 16 + c15) * 40 + khi];
        #pragma unroll
        for (int f = 0; f < 5; ++f) {
            bf16x8 b = *(const bf16x8*)&B_lds[cur][(w * 80 + f * 16 + c15) * 40 + khi];
            #pragma unroll
            for (int mf = 0; mf < 4; ++mf)
                acc[mf][f] = __builtin_amdgcn_mfma_f32_16x16x32_bf16(a[mf], b, acc[mf][f], 0, 0, 0);
        }
        if (k < 2) {
            const int nxt = cur ^ 1;
            ushort* d = &A_lds[nxt][r * 40 + p];
            d[0]=f2bf(a0.x); d[1]=f2bf(a0.y); d[2]=f2bf(a0.z); d[3]=f2bf(a0.w);
            d[4]=f2bf(a1.x); d[5]=f2bf(a1.y); d[6]=f2bf(a1.z); d[7]=f2bf(a1.w);
            #pragma unroll
            for (int i = 0; i < 5; ++i) {
                int idx = tid + i * 256; int n = idx >> 2, q = (idx & 3) * 8;
                *(ushort8*)&B_lds[nxt][n * 40 + q] = breg[i];
            }
            __syncthreads();
        }
    }
    float* dst = part + (size_t)(mat * 8 + ks) * 640 * 320;
    #pragma unroll
    for (int mf = 0; mf < 4; ++mf)
        #pragma unroll
        for (int f = 0; f < 5; ++f) {
            int col = w * 80 + f * 16 + c15;
            #pragma unroll
            for (int rr = 0; rr < 4; ++rr)
                dst[(size_t)(m0 + mf * 16 + rbase + rr) * 320 + col] = acc[mf][f][rr];
        }
}

// ---------------------------------------------------------------------------
// Reduce 8 split-K partials -> Kf (frag order, qb<5) / Vf (frag, bt<5) /
// VVt raw (bt>=5, vprime input).
// ---------------------------------------------------------------------------
__global__ __launch_bounds__(256) void kv_reduce(
    const float* __restrict__ part, ushort* __restrict__ Kf,
    ushort* __restrict__ Vf, ushort* __restrict__ VVt)
{
    int idx = blockIdx.x * 256 + threadIdx.x;
    if (idx >= 616 * 320) return;
    int mat = blockIdx.y;
    int row = idx / 320, col = idx - row * 320;
    float s8 = 0.f;
    #pragma unroll
    for (int ks = 0; ks < 8; ++ks)
        s8 += part[((size_t)(mat * 8 + ks) * 640 + row) * 320 + col];
    ushort b = f2bf(s8);
    int bt = row / 77, s = row - bt * 77;
    int h = col / 40, kd = col - h * 40;
    if (mat == 0) {
        if (bt < 5) {
            int kt = kd >> 5, chunk = (kd >> 3) & 3;
            int lane = (s & 15) | (chunk << 4);
            Kf[((size_t)((bt * 8 + h) * 5 + (s >> 4)) * 2 + kt) * 512 + lane * 8 + (kd & 7)] = b;
        }
    } else {
        if (bt < 5) {
            int lane = (kd & 15) | (((s >> 3) & 3) << 4);
            Vf[(((size_t)(bt * 8 + h) * 3 + (kd >> 4)) * 3 + (s >> 5)) * 512 + lane * 8 + (s & 7)] = b;
        } else {
            VVt[((size_t)bt * 320 + col) * 80 + s] = b;
        }
    }
}

// ---------------------------------------------------------------------------
// v'[p][m][c] = sum_e mapper[p][m][e] * V[5+p][e][c] -> VPf (frag order).
// ---------------------------------------------------------------------------
__global__ void vprime_k(const float* __restrict__ mapper, const ushort* __restrict__ VVt,
                         ushort* __restrict__ VPf)
{
    int pm = blockIdx.x;            // p*77 + m
    int p = pm / 77, m = pm - p * 77;
    __shared__ float mp[77];
    int tid = threadIdx.x;          // 320 threads, one per channel c
    if (tid < 77) mp[tid] = mapper[(size_t)pm * 77 + tid];
    __syncthreads();
    const ushort* vrow = VVt + ((size_t)(5 + p) * 320 + tid) * 80;
    float acc = 0.f;
    for (int e = 0; e < 77; ++e) acc += mp[e] * bf2f(vrow[e]);
    int h = tid / 40, dc = tid - h * 40;
    int lane = (dc & 15) | (((m >> 3) & 3) << 4);
    VPf[(((size_t)(p * 8 + h) * 3 + (dc >> 4)) * 3 + (m >> 5)) * 512 + lane * 8 + (m & 7)] = f2bf(acc);
}

// ---------------------------------------------------------------------------
// FUSED q-projection + attention + out-projection, v8.
// grid = (T/64, BT=8), 512 thr (8 waves). Per block:
//  1) stage hs[qb, 64 rows] f32->bf16 into AO_lds (coalesced)      [barrier]
//  2) wave (rg,half): Q-GEMM 16 rows x 160 cols vs Wqf frags       [barrier]
//     write Q back to AO_lds in C-layout (wave-private rows+cols)
//  3) per head: qa from LDS (own region), K/V frags from global, softmax,
//     PV -> AO overwrites Q head h after it is consumed (wave-private)
//  4) [barrier] out-projection vs Wof frags; f32 out + bias.
// 3 barriers total; all global operand loads are coalesced fragment loads.
// ---------------------------------------------------------------------------
#define ATT_SCALE 0.15811388300841897f   // 1/sqrt(40)
__global__ __launch_bounds__(512, 4) void attn_out_k(
    const float* __restrict__ hs, const ushort* __restrict__ Wqf,
    const ushort* __restrict__ Kf, const ushort* __restrict__ Vf,
    const ushort* __restrict__ VPf, const ushort* __restrict__ Wof,
    const float* __restrict__ bias, float* __restrict__ out)
{
    __shared__ __align__(16) ushort AO_lds[64 * 328];     // 41,984 B
    __shared__ __align__(16) ushort P_lds[8 * 16 * 104];  // 26,624 B

    const int tid = threadIdx.x;
    const int ww = tid >> 6, l = tid & 63;
    const int rg = ww & 3, half = ww >> 2;
    const int c15 = l & 15, hi4 = l >> 4;
    const int khi = hi4 * 8, rbase = hi4 * 4;
    const int bt = blockIdx.y, t0 = blockIdx.x * 64;
    const int qb = (bt < 5) ? bt : 4;
    const ushort* Vfb = (bt < 5) ? (Vf + (size_t)bt * (8 * 3 * 3 * 512))
                                 : (VPf + (size_t)(bt - 5) * (8 * 3 * 3 * 512));
    const ushort8 z8 = {0,0,0,0,0,0,0,0};
    ushort* Pw = P_lds + ww * (16 * 104);       // wave-private P tile

    if (l < 48) {   // zero P pad cols 80..103
        int r = l / 3, c = l - 3 * (l / 3);
        *(ushort8*)&Pw[r * 104 + 80 + c * 8] = z8;
    }

    // ---- 1) stage hs tile (f32 -> bf16) into AO_lds ----
    for (int i = tid; i < 2560; i += 512) {     // 64 rows x 40 chunks
        int r = i / 40, cc = i - (i / 40) * 40;
        const float4v* s = (const float4v*)(hs + (size_t)(qb * 4096 + t0 + r) * 320 + cc * 8);
        float4v x0 = s[0], x1 = s[1];
        ushort* d = &AO_lds[r * 328 + cc * 8];
        d[0]=f2bf(x0.x); d[1]=f2bf(x0.y); d[2]=f2bf(x0.z); d[3]=f2bf(x0.w);
        d[4]=f2bf(x1.x); d[5]=f2bf(x1.y); d[6]=f2bf(x1.z); d[7]=f2bf(x1.w);
    }
    __syncthreads();

    // ---- 2) Q-GEMM: wave computes rows rg*16..+16, cols half*160..+160 ----
    const int cb = half * 160;
    {
        f32x4 qacc[10] = {};
        for (int kk = 0; kk < 10; ++kk) {
            bf16x8 a = *(const bf16x8*)&AO_lds[(rg * 16 + c15) * 328 + kk * 32 + khi];
            const ushort* wb = Wqf + (size_t)((kk * 2 + half) * 10) * 512 + l * 8;
            #pragma unroll
            for (int f = 0; f < 10; ++f)
                qacc[f] = __builtin_amdgcn_mfma_f32_16x16x32_bf16(
                    a, *(const bf16x8*)(wb + (size_t)f * 512), qacc[f], 0, 0, 0);
        }
        __syncthreads();    // all hs-tile reads complete before overwrite
        #pragma unroll
        for (int f = 0; f < 10; ++f) {
            int col = cb + f * 16 + c15;
            #pragma unroll
            for (int rr = 0; rr < 4; ++rr)
                AO_lds[(rg * 16 + rbase + rr) * 328 + col] = f2bf(qacc[f][rr]);
        }
        // no barrier: all subsequent Q reads are wave-private (own rows+cols)
    }

    // ---- 3) per-head attention ----
    for (int hh = 0; hh < 4; ++hh) {
        const int h = half * 4 + hh;

        // qa frags from LDS (wave-private; k 32..39 only valid for hi4==0)
        bf16x8 qa0 = *(const bf16x8*)&AO_lds[(rg * 16 + c15) * 328 + h * 40 + khi];
        bf16x8 qa1 = {0,0,0,0,0,0,0,0};
        if (hi4 == 0) qa1 = *(const bf16x8*)&AO_lds[(rg * 16 + c15) * 328 + h * 40 + 32];

        // QK^T
        f32x4 sacc[5] = {};
        #pragma unroll
        for (int f = 0; f < 5; ++f) {
            const ushort* kfb = Kf + ((size_t)((qb * 8 + h) * 5 + f) * 2) * 512 + l * 8;
            bf16x8 kb0 = *(const bf16x8*)(kfb);
            bf16x8 kb1 = *(const bf16x8*)(kfb + 512);
            sacc[f] = __builtin_amdgcn_mfma_f32_16x16x32_bf16(qa0, kb0, sacc[f], 0, 0, 0);
            sacc[f] = __builtin_amdgcn_mfma_f32_16x16x32_bf16(qa1, kb1, sacc[f], 0, 0, 0);
        }

        // V frags (latency hides under softmax)
        bf16x8 vreg[3][3];
        #pragma unroll
        for (int f = 0; f < 3; ++f)
            #pragma unroll
            for (int kt = 0; kt < 3; ++kt)
                vreg[f][kt] = *(const bf16x8*)(Vfb + (((size_t)(h * 3 + f) * 3 + kt)) * 512 + l * 8);

        // softmax, no max pass (scores tiny); 16-lane sum reduce
        float pv[5][4];
        #pragma unroll
        for (int r = 0; r < 4; ++r) {
            float sum = 0.f;
            #pragma unroll
            for (int f = 0; f < 5; ++f) {
                bool valid = (f < 4) || (c15 < 13);     // col = 16f + c15 < 77
                float e = valid ? __expf(sacc[f][r] * ATT_SCALE) : 0.f;
                pv[f][r] = e; sum += e;
            }
            #pragma unroll
            for (int d = 1; d < 16; d <<= 1) sum += __shfl_xor(sum, d);
            float inv = 1.f / sum;
            #pragma unroll
            for (int f = 0; f < 5; ++f) pv[f][r] *= inv;
        }

        // P write (wave-private LDS; intra-wave ordering, no barrier)
        #pragma unroll
        for (int r = 0; r < 4; ++r)
            #pragma unroll
            for (int f = 0; f < 5; ++f)
                Pw[(rbase + r) * 104 + f * 16 + c15] = f2bf(pv[f][r]);

        // PV: P from own LDS tile (A), V from regs (B)
        bf16x8 pa[3];
        #pragma unroll
        for (int kt = 0; kt < 3; ++kt)
            pa[kt] = *(const bf16x8*)&Pw[c15 * 104 + kt * 32 + khi];
        f32x4 oacc[3] = {};
        #pragma unroll
        for (int f = 0; f < 3; ++f)
            #pragma unroll
            for (int kt = 0; kt < 3; ++kt)
                oacc[f] = __builtin_amdgcn_mfma_f32_16x16x32_bf16(pa[kt], vreg[f][kt], oacc[f], 0, 0, 0);

        // AO write for head h (overwrites consumed Q head h; wave-private)
        #pragma unroll
        for (int f = 0; f < 3; ++f) {
            int col = f * 16 + c15;
            if (col < 40) {
                #pragma unroll
                for (int r = 0; r < 4; ++r)
                    AO_lds[(rg * 16 + rbase + r) * 328 + h * 40 + col] = f2bf(oacc[f][r]);
            }
        }
    }
    __syncthreads();    // AO complete block-wide

    // ---- 4) out-projection: rows rg*16..+16, cols half*160..+160, K=320 ----
    f32x4 acc[10] = {};
    for (int kk = 0; kk < 10; ++kk) {
        bf16x8 a = *(const bf16x8*)&AO_lds[(rg * 16 + c15) * 328 + kk * 32 + khi];
        const ushort* wb = Wof + (size_t)((kk * 2 + half) * 10) * 512 + l * 8;
        #pragma unroll
        for (int f = 0; f < 10; ++f) {
            bf16x8 b = *(const bf16x8*)(wb + (size_t)f * 512);
            acc[f] = __builtin_amdgcn_mfma_f32_16x16x32_bf16(a, b, acc[f], 0, 0, 0);
        }
    }

    // ---- epilogue ----
    #pragma unroll
    for (int f = 0; f < 10; ++f) {
        int col = cb + f * 16 + c15;
        #pragma unroll
        for (int rr = 0; rr < 4; ++rr)
            out[(size_t)(bt * 4096 + t0 + rg * 16 + rbase + rr) * 320 + col]
                = acc[f][rr] + bias[col];
    }
}

// ---------------------------------------------------------------------------
extern "C" void kernel_launch(void* const* d_in, const int* in_sizes, int n_in,
                              void* d_out, int out_size, void* d_ws, size_t ws_size,
                              hipStream_t stream) {
    (void)in_sizes; (void)n_in; (void)out_size; (void)ws_size;
    const float* hs     = (const float*)d_in[0];   // (8,4096,320)
    const float* ehs    = (const float*)d_in[1];   // (8,77,768)
    const float* mapper = (const float*)d_in[2];   // (3,77,77)
    const float* Wq     = (const float*)d_in[3];   // (320,320)
    const float* Wk     = (const float*)d_in[4];   // (768,320)
    const float* Wv     = (const float*)d_in[5];   // (768,320)
    const float* Wo     = (const float*)d_in[6];   // (320,320)
    const float* bo     = (const float*)d_in[7];   // (320,)
    float* out = (float*)d_out;

    ushort* ws   = (ushort*)d_ws;
    ushort* Wq_t = ws;                             // 320*320
    ushort* Wk_t = Wq_t + 320 * 320;               // 320*768
    ushort* Wv_t = Wk_t + 320 * 768;               // 320*768
    ushort* Wo_t = Wv_t + 320 * 768;               // 320*320
    ushort* Wof  = Wo_t + 320 * 320;               // WF_SZ
    ushort* Wqf  = Wof + WF_SZ;                    // WF_SZ
    ushort* Kfb  = Wqf + WF_SZ;                    // KF_SZ
    ushort* Vfb  = Kfb + KF_SZ;                    // VF_SZ
    ushort* VPfb = Vfb + VF_SZ;                    // VPF_SZ
    ushort* VVt  = VPfb + VPF_SZ;                  // 8*320*80 raw (bt>=5 used)
    float*  part = (float*)(VVt + 8 * 320 * 80);   // 16*640*320 f32 = 13.1 MB

    prep_k<<<1069, 256, 0, stream>>>(Wq, Wk, Wv, Wo, Wq_t, Wk_t, Wv_t, Wo_t,
                                     Kfb, Vfb, VPfb);
    gemm_kv<<<260, 256, 0, stream>>>(ehs, Wk_t, Wv_t, Wq_t, Wo_t, part, Wof, Wqf);
    kv_reduce<<<dim3(770, 2), 256, 0, stream>>>(part, Kfb, Vfb, VVt);
    vprime_k<<<231, 320, 0, stream>>>(mapper, VVt, VPfb);
    attn_out_k<<<dim3(64, 8), 512, 0, stream>>>(hs, Wqf, Kfb, Vfb, VPfb, Wof, bo, out);
}

// Round 16
// 65.288 us; speedup vs baseline: 1.1402x; 1.1402x over previous
//
#include <hip/hip_runtime.h>
#include <hip/hip_bf16.h>

typedef unsigned short ushort;
typedef __attribute__((ext_vector_type(8))) short bf16x8;     // MFMA A/B frag (8 bf16)
typedef __attribute__((ext_vector_type(8))) unsigned short ushort8;
typedef __attribute__((ext_vector_type(4))) float f32x4;      // MFMA C/D frag
typedef __attribute__((ext_vector_type(4))) float float4v;

__device__ __forceinline__ ushort f2bf(float f) {
    union { float f; unsigned u; } v; v.f = f;
    unsigned r = v.u + 0x7FFFu + ((v.u >> 16) & 1u);
    return (ushort)(r >> 16);
}
__device__ __forceinline__ float bf2f(ushort u) {
    union { unsigned u; float f; } v; v.u = ((unsigned)u) << 16;
    return v.f;
}

// Fragment-buffer geometry (ushort offsets; each frag = 64 lanes x 8 elems = 512)
//  Qf : ((rowgrp*8 + h)*2 + kt)*512 + lane*8 + e       rowgrp<1280
//  Kf : (((qb*8 + h)*5 + f)*2 + kt)*512 + lane*8 + e   qb<5
//  Vf : (((vb*8 + h)*3 + f)*3 + kt)*512 + lane*8 + e   vb<5   (VPf: vb=p<3)
//  Wof: ((kk*2 + half)*10 + f)*512 + lane*8 + e        kk<10, half<2, f<10
#define QF_SZ   (1280u * 8 * 2 * 512)      // 10,485,760
#define KF_SZ   (5u * 8 * 5 * 2 * 512)     //    204,800
#define VF_SZ   (5u * 8 * 3 * 3 * 512)     //    368,640
#define VPF_SZ  (3u * 8 * 3 * 3 * 512)     //    221,184
#define WF_SZ   (10u * 2 * 10 * 512)       //    102,400

// ---------------------------------------------------------------------------
// Weight transpose (blocks 0..679) + frag-buffer zero-fill (blocks 680..1068).
// ---------------------------------------------------------------------------
__global__ __launch_bounds__(256) void prep_k(
    const float* __restrict__ Wq, const float* __restrict__ Wk,
    const float* __restrict__ Wv, const float* __restrict__ Wo,
    ushort* __restrict__ Wq_t, ushort* __restrict__ Wk_t,
    ushort* __restrict__ Wv_t, ushort* __restrict__ Wo_t,
    ushort* __restrict__ Kf, ushort* __restrict__ Vf, ushort* __restrict__ VPf)
{
    int b = blockIdx.x;
    if (b >= 680) {         // zero-fill pads
        const ushort8 z8 = {0,0,0,0,0,0,0,0};
        unsigned i = (b - 680) * 256 + threadIdx.x;
        if (i < KF_SZ / 8) ((ushort8*)Kf)[i] = z8;
        else if (i < (KF_SZ + VF_SZ) / 8) ((ushort8*)Vf)[i - KF_SZ / 8] = z8;
        else if (i < (KF_SZ + VF_SZ + VPF_SZ) / 8) ((ushort8*)VPf)[i - (KF_SZ + VF_SZ) / 8] = z8;
        return;
    }
    __shared__ ushort t[32][33];
    const float* src; ushort* dst; int K; int tb;
    if (b < 100)      { src = Wq; dst = Wq_t; K = 320; tb = b; }
    else if (b < 340) { src = Wk; dst = Wk_t; K = 768; tb = b - 100; }
    else if (b < 580) { src = Wv; dst = Wv_t; K = 768; tb = b - 340; }
    else              { src = Wo; dst = Wo_t; K = 320; tb = b - 580; }
    int tc = tb % 10, tr = tb / 10;
    int tx = threadIdx.x & 31, ty = threadIdx.x >> 5;
    #pragma unroll
    for (int p = 0; p < 4; ++p) {
        int k = tr * 32 + ty + p * 8, n = tc * 32 + tx;
        t[ty + p * 8][tx] = f2bf(src[(size_t)k * 320 + n]);
    }
    __syncthreads();
    #pragma unroll
    for (int p = 0; p < 4; ++p) {
        int n = tc * 32 + ty + p * 8, k = tr * 32 + tx;
        dst[(size_t)n * K + k] = t[tx][ty + p * 8];
    }
}

// ---------------------------------------------------------------------------
// Fused q-projection (frag-order out) + split-K k/v partials + Wof formatter.
// bid<160: kv partial; 160<=bid<480: qproj; bid>=480: Wof format (50 blocks).
// ---------------------------------------------------------------------------
__global__ __launch_bounds__(256) void gemm_qkv(
    const float* __restrict__ A, const ushort* __restrict__ Wq_t,
    const float* __restrict__ E, const ushort* __restrict__ Wk_t,
    const ushort* __restrict__ Wv_t, const ushort* __restrict__ Wo_t,
    ushort* __restrict__ Qf, float* __restrict__ part, ushort* __restrict__ Wof)
{
    const int tid = threadIdx.x;
    const int bid = blockIdx.x;
    if (bid >= 480) {       // Wof: frag g = chunk/64, lane = chunk%64
        int i = (bid - 480) * 256 + tid;        // 12800 chunks of 8 ushorts
        int g = i >> 6, l = i & 63;
        int kk = g / 20, half = (g / 10) & 1, f = g % 10;
        int n = half * 160 + f * 16 + (l & 15);
        int k0 = kk * 32 + (l >> 4) * 8;
        *(ushort8*)(Wof + (size_t)g * 512 + l * 8) =
            *(const ushort8*)(Wo_t + (size_t)n * 320 + k0);
        return;
    }
    __shared__ ushort A_lds[2][64 * 40];
    __shared__ ushort B_lds[2][320 * 40];
    const int w = tid >> 6, l = tid & 63;
    const int c15 = l & 15, khi = (l >> 4) * 8;
    const int r = tid >> 2, p = (tid & 3) * 8;
    const int rbase = (l >> 4) * 4;
    f32x4 acc[4][5] = {};
    const ushort8 z8 = {0,0,0,0,0,0,0,0};

    if (bid < 160) {
        const int mtile = bid % 10, mat = (bid / 10) & 1, ks = bid / 20;
        const int m0 = mtile * 64, kk0 = ks * 96;
        const ushort* Bt = mat ? Wv_t : Wk_t;
        const int m = m0 + r;
        const bool live = (m < 616);
        const float* Abase = E + (size_t)(live ? m : 0) * 768 + p;
        float4v a0 = {0,0,0,0}, a1 = {0,0,0,0};
        ushort8 breg[5];
        if (live) { a0 = *(const float4v*)(Abase + kk0); a1 = *(const float4v*)(Abase + kk0 + 4); }
        #pragma unroll
        for (int i = 0; i < 5; ++i) {
            int idx = tid + i * 256; int n = idx >> 2, q = (idx & 3) * 8;
            breg[i] = *(const ushort8*)(Bt + (size_t)n * 768 + kk0 + q);
        }
        {
            ushort* d = &A_lds[0][r * 40 + p];
            d[0]=f2bf(a0.x); d[1]=f2bf(a0.y); d[2]=f2bf(a0.z); d[3]=f2bf(a0.w);
            d[4]=f2bf(a1.x); d[5]=f2bf(a1.y); d[6]=f2bf(a1.z); d[7]=f2bf(a1.w);
            #pragma unroll
            for (int i = 0; i < 5; ++i) {
                int idx = tid + i * 256; int n = idx >> 2, q = (idx & 3) * 8;
                *(ushort8*)&B_lds[0][n * 40 + q] = breg[i];
            }
        }
        __syncthreads();
        for (int k = 0; k < 3; ++k) {
            const int cur = k & 1;
            if (k < 2) {
                int kk = kk0 + (k + 1) * 32;
                if (live) { a0 = *(const float4v*)(Abase + kk); a1 = *(const float4v*)(Abase + kk + 4); }
                #pragma unroll
                for (int i = 0; i < 5; ++i) {
                    int idx = tid + i * 256; int n = idx >> 2, q = (idx & 3) * 8;
                    breg[i] = *(const ushort8*)(Bt + (size_t)n * 768 + kk + q);
                }
            }
            bf16x8 a[4];
            #pragma unroll
            for (int mf = 0; mf < 4; ++mf)
                a[mf] = *(const bf16x8*)&A_lds[cur][(mf * 16 + c15) * 40 + khi];
            #pragma unroll
            for (int f = 0; f < 5; ++f) {
                bf16x8 b = *(const bf16x8*)&B_lds[cur][(w * 80 + f * 16 + c15) * 40 + khi];
                #pragma unroll
                for (int mf = 0; mf < 4; ++mf)
                    acc[mf][f] = __builtin_amdgcn_mfma_f32_16x16x32_bf16(a[mf], b, acc[mf][f], 0, 0, 0);
            }
            if (k < 2) {
                const int nxt = cur ^ 1;
                ushort* d = &A_lds[nxt][r * 40 + p];
                d[0]=f2bf(a0.x); d[1]=f2bf(a0.y); d[2]=f2bf(a0.z); d[3]=f2bf(a0.w);
                d[4]=f2bf(a1.x); d[5]=f2bf(a1.y); d[6]=f2bf(a1.z); d[7]=f2bf(a1.w);
                #pragma unroll
                for (int i = 0; i < 5; ++i) {
                    int idx = tid + i * 256; int n = idx >> 2, q = (idx & 3) * 8;
                    *(ushort8*)&B_lds[nxt][n * 40 + q] = breg[i];
                }
                __syncthreads();
            }
        }
        float* dst = part + (size_t)(mat * 8 + ks) * 640 * 320;
        #pragma unroll
        for (int mf = 0; mf < 4; ++mf)
            #pragma unroll
            for (int f = 0; f < 5; ++f) {
                int col = w * 80 + f * 16 + c15;
                #pragma unroll
                for (int rr = 0; rr < 4; ++rr)
                    dst[(size_t)(m0 + mf * 16 + rbase + rr) * 320 + col] = acc[mf][f][rr];
            }
    } else {
        const int m0 = (bid - 160) * 64;
        const float* Abase = A + (size_t)(m0 + r) * 320 + p;
        float4v a0, a1; ushort8 breg[5];
        a0 = *(const float4v*)(Abase + 0);
        a1 = *(const float4v*)(Abase + 4);
        #pragma unroll
        for (int i = 0; i < 5; ++i) {
            int idx = tid + i * 256; int n = idx >> 2, q = (idx & 3) * 8;
            breg[i] = *(const ushort8*)(Wq_t + (size_t)n * 320 + q);
        }
        {
            ushort* d = &A_lds[0][r * 40 + p];
            d[0]=f2bf(a0.x); d[1]=f2bf(a0.y); d[2]=f2bf(a0.z); d[3]=f2bf(a0.w);
            d[4]=f2bf(a1.x); d[5]=f2bf(a1.y); d[6]=f2bf(a1.z); d[7]=f2bf(a1.w);
            #pragma unroll
            for (int i = 0; i < 5; ++i) {
                int idx = tid + i * 256; int n = idx >> 2, q = (idx & 3) * 8;
                *(ushort8*)&B_lds[0][n * 40 + q] = breg[i];
            }
        }
        __syncthreads();
        for (int k = 0; k < 10; ++k) {
            const int cur = k & 1;
            if (k < 9) {
                int kk = (k + 1) * 32;
                a0 = *(const float4v*)(Abase + kk);
                a1 = *(const float4v*)(Abase + kk + 4);
                #pragma unroll
                for (int i = 0; i < 5; ++i) {
                    int idx = tid + i * 256; int n = idx >> 2, q = (idx & 3) * 8;
                    breg[i] = *(const ushort8*)(Wq_t + (size_t)n * 320 + kk + q);
                }
            }
            bf16x8 a[4];
            #pragma unroll
            for (int mf = 0; mf < 4; ++mf)
                a[mf] = *(const bf16x8*)&A_lds[cur][(mf * 16 + c15) * 40 + khi];
            #pragma unroll
            for (int f = 0; f < 5; ++f) {
                bf16x8 b = *(const bf16x8*)&B_lds[cur][(w * 80 + f * 16 + c15) * 40 + khi];
                #pragma unroll
                for (int mf = 0; mf < 4; ++mf)
                    acc[mf][f] = __builtin_amdgcn_mfma_f32_16x16x32_bf16(a[mf], b, acc[mf][f], 0, 0, 0);
            }
            if (k < 9) {
                const int nxt = cur ^ 1;
                ushort* d = &A_lds[nxt][r * 40 + p];
                d[0]=f2bf(a0.x); d[1]=f2bf(a0.y); d[2]=f2bf(a0.z); d[3]=f2bf(a0.w);
                d[4]=f2bf(a1.x); d[5]=f2bf(a1.y); d[6]=f2bf(a1.z); d[7]=f2bf(a1.w);
                #pragma unroll
                for (int i = 0; i < 5; ++i) {
                    int idx = tid + i * 256; int n = idx >> 2, q = (idx & 3) * 8;
                    *(ushort8*)&B_lds[nxt][n * 40 + q] = breg[i];
                }
                __syncthreads();
            }
        }
        // zero slots: kt=1 lanes 16..63 for rowgrps m0/16..+3, all h
        const int rg0 = m0 >> 4;
        for (int i = tid; i < 1536; i += 256) {
            int grp = i / 48;                   // rg4*8 + h
            int lane16 = 16 + (i - grp * 48);
            int rg4 = grp >> 3, h = grp & 7;
            *(ushort8*)(Qf + ((size_t)((rg0 + rg4) * 8 + h) * 2 + 1) * 512 + lane16 * 8) = z8;
        }
        // data writes in fragment order
        #pragma unroll
        for (int mf = 0; mf < 4; ++mf)
            #pragma unroll
            for (int f = 0; f < 5; ++f) {
                int col = w * 80 + f * 16 + c15;
                int h = col / 40, kd = col - h * 40;
                int kt = kd >> 5, chunk = (kd >> 3) & 3, elem = kd & 7;
                size_t base = ((size_t)((rg0 + mf) * 8 + h) * 2 + kt) * 512;
                #pragma unroll
                for (int rr = 0; rr < 4; ++rr) {
                    int lane = (rbase + rr) | (chunk << 4);
                    Qf[base + lane * 8 + elem] = f2bf(acc[mf][f][rr]);
                }
            }
    }
}

// ---------------------------------------------------------------------------
// Reduce 8 split-K partials -> Kf (frag order, qb<5) / Vf (frag, bt<5) /
// VVt raw (bt>=5, vprime input).
// ---------------------------------------------------------------------------
__global__ __launch_bounds__(256) void kv_reduce(
    const float* __restrict__ part, ushort* __restrict__ Kf,
    ushort* __restrict__ Vf, ushort* __restrict__ VVt)
{
    int idx = blockIdx.x * 256 + threadIdx.x;
    if (idx >= 616 * 320) return;
    int mat = blockIdx.y;
    int row = idx / 320, col = idx - row * 320;
    float s8 = 0.f;
    #pragma unroll
    for (int ks = 0; ks < 8; ++ks)
        s8 += part[((size_t)(mat * 8 + ks) * 640 + row) * 320 + col];
    ushort b = f2bf(s8);
    int bt = row / 77, s = row - bt * 77;
    int h = col / 40, kd = col - h * 40;
    if (mat == 0) {
        if (bt < 5) {
            int kt = kd >> 5, chunk = (kd >> 3) & 3;
            int lane = (s & 15) | (chunk << 4);
            Kf[((size_t)((bt * 8 + h) * 5 + (s >> 4)) * 2 + kt) * 512 + lane * 8 + (kd & 7)] = b;
        }
    } else {
        if (bt < 5) {
            int lane = (kd & 15) | (((s >> 3) & 3) << 4);
            Vf[(((size_t)(bt * 8 + h) * 3 + (kd >> 4)) * 3 + (s >> 5)) * 512 + lane * 8 + (s & 7)] = b;
        } else {
            VVt[((size_t)bt * 320 + col) * 80 + s] = b;
        }
    }
}

// ---------------------------------------------------------------------------
// v'[p][m][c] = sum_e mapper[p][m][e] * V[5+p][e][c] -> VPf (frag order).
// ---------------------------------------------------------------------------
__global__ void vprime_k(const float* __restrict__ mapper, const ushort* __restrict__ VVt,
                         ushort* __restrict__ VPf)
{
    int pm = blockIdx.x;            // p*77 + m
    int p = pm / 77, m = pm - p * 77;
    __shared__ float mp[77];
    int tid = threadIdx.x;          // 320 threads, one per channel c
    if (tid < 77) mp[tid] = mapper[(size_t)pm * 77 + tid];
    __syncthreads();
    const ushort* vrow = VVt + ((size_t)(5 + p) * 320 + tid) * 80;
    float acc = 0.f;
    for (int e = 0; e < 77; ++e) acc += mp[e] * bf2f(vrow[e]);
    int h = tid / 40, dc = tid - h * 40;
    int lane = (dc & 15) | (((m >> 3) & 3) << 4);
    VPf[(((size_t)(p * 8 + h) * 3 + (dc >> 4)) * 3 + (m >> 5)) * 512 + lane * 8 + (m & 7)] = f2bf(acc);
}

// ---------------------------------------------------------------------------
// FUSED attention + out-projection, v9. grid = (T/64, BT=8), 512 thr (8 waves).
// ATTENTION: wave = HEAD (ww = h) — each wave processes its head for all 64
// rows (4 row-group iterations). K frags preloaded once/wave; V loaded per-f.
// => zero intra-block duplicate K/V L2 reads, zero attention barriers
// (P wave-private; AO column range h*40..+40 wave-private).
// OUT-PROJ: wave = (rg, half); Wof staged per-kk into LDS (aliases dead P
// region) so each block reads Wof exactly once (was 4x redundant).
// ---------------------------------------------------------------------------
#define ATT_SCALE 0.15811388300841897f   // 1/sqrt(40)
__global__ __launch_bounds__(512, 4) void attn_out_k(
    const ushort* __restrict__ Qf, const ushort* __restrict__ Kf,
    const ushort* __restrict__ Vf, const ushort* __restrict__ VPf,
    const ushort* __restrict__ Wof, const float* __restrict__ bias,
    float* __restrict__ out)
{
    __shared__ __align__(16) ushort AO_lds[64 * 328];     // 41,984 B
    __shared__ __align__(16) ushort P_lds[8 * 16 * 104];  // 26,624 B
    ushort* W_lds = P_lds;                                // outproj alias (20 KB/kk)

    const int tid = threadIdx.x;
    const int ww = tid >> 6, l = tid & 63;
    const int c15 = l & 15, hi4 = l >> 4;
    const int khi = hi4 * 8, rbase = hi4 * 4;
    const int bt = blockIdx.y;
    const int qb = (bt < 5) ? bt : 4;
    const int h = ww;                            // wave = head
    const ushort* Vfb = (bt < 5) ? (Vf + (size_t)bt * (8 * 3 * 3 * 512))
                                 : (VPf + (size_t)(bt - 5) * (8 * 3 * 3 * 512));
    const ushort8 z8 = {0,0,0,0,0,0,0,0};
    ushort* Pw = P_lds + ww * (16 * 104);        // wave-private P tile

    if (l < 48) {   // zero P pad cols 80..103 (16 rows x 3 chunks)
        int r = l / 3, c = l - 3 * (l / 3);
        *(ushort8*)&Pw[r * 104 + 80 + c * 8] = z8;
    }

    // ---- preload K frags for this head (once; no intra-block redundancy) ----
    bf16x8 kreg[5][2];
    #pragma unroll
    for (int f = 0; f < 5; ++f) {
        const ushort* kfb = Kf + ((size_t)((qb * 8 + h) * 5 + f) * 2) * 512 + l * 8;
        kreg[f][0] = *(const bf16x8*)(kfb);
        kreg[f][1] = *(const bf16x8*)(kfb + 512);
    }

    // ---- attention: 4 row-group iterations, zero barriers ----
    for (int rg4 = 0; rg4 < 4; ++rg4) {
        const int rowgrp = qb * 256 + blockIdx.x * 4 + rg4;

        bf16x8 qa0 = *(const bf16x8*)(Qf + ((size_t)(rowgrp * 8 + h) * 2 + 0) * 512 + l * 8);
        bf16x8 qa1 = *(const bf16x8*)(Qf + ((size_t)(rowgrp * 8 + h) * 2 + 1) * 512 + l * 8);

        f32x4 sacc[5] = {};
        #pragma unroll
        for (int f = 0; f < 5; ++f) {
            sacc[f] = __builtin_amdgcn_mfma_f32_16x16x32_bf16(qa0, kreg[f][0], sacc[f], 0, 0, 0);
            sacc[f] = __builtin_amdgcn_mfma_f32_16x16x32_bf16(qa1, kreg[f][1], sacc[f], 0, 0, 0);
        }

        // softmax, no max pass (scores tiny); 16-lane sum reduce
        float pv[5][4];
        #pragma unroll
        for (int r = 0; r < 4; ++r) {
            float sum = 0.f;
            #pragma unroll
            for (int f = 0; f < 5; ++f) {
                bool valid = (f < 4) || (c15 < 13);     // col = 16f + c15 < 77
                float e = valid ? __expf(sacc[f][r] * ATT_SCALE) : 0.f;
                pv[f][r] = e; sum += e;
            }
            #pragma unroll
            for (int d = 1; d < 16; d <<= 1) sum += __shfl_xor(sum, d);
            float inv = 1.f / sum;
            #pragma unroll
            for (int f = 0; f < 5; ++f) pv[f][r] *= inv;
        }

        // P write (wave-private LDS; intra-wave ordering, no barrier)
        #pragma unroll
        for (int r = 0; r < 4; ++r)
            #pragma unroll
            for (int f = 0; f < 5; ++f)
                Pw[(rbase + r) * 104 + f * 16 + c15] = f2bf(pv[f][r]);

        // PV: P from own LDS tile (A), V frags loaded per-f (B)
        bf16x8 pa[3];
        #pragma unroll
        for (int kt = 0; kt < 3; ++kt)
            pa[kt] = *(const bf16x8*)&Pw[c15 * 104 + kt * 32 + khi];
        f32x4 oacc[3];
        #pragma unroll
        for (int f = 0; f < 3; ++f) {
            bf16x8 v0 = *(const bf16x8*)(Vfb + (((size_t)(h * 3 + f) * 3 + 0)) * 512 + l * 8);
            bf16x8 v1 = *(const bf16x8*)(Vfb + (((size_t)(h * 3 + f) * 3 + 1)) * 512 + l * 8);
            bf16x8 v2 = *(const bf16x8*)(Vfb + (((size_t)(h * 3 + f) * 3 + 2)) * 512 + l * 8);
            f32x4 o = {};
            o = __builtin_amdgcn_mfma_f32_16x16x32_bf16(pa[0], v0, o, 0, 0, 0);
            o = __builtin_amdgcn_mfma_f32_16x16x32_bf16(pa[1], v1, o, 0, 0, 0);
            o = __builtin_amdgcn_mfma_f32_16x16x32_bf16(pa[2], v2, o, 0, 0, 0);
            oacc[f] = o;
        }

        // AO write (cols h*40..+40 are wave-private; rows rg4*16..+16)
        #pragma unroll
        for (int f = 0; f < 3; ++f) {
            int col = f * 16 + c15;
            if (col < 40) {
                #pragma unroll
                for (int r = 0; r < 4; ++r)
                    AO_lds[(rg4 * 16 + rbase + r) * 328 + h * 40 + col] = f2bf(oacc[f][r]);
            }
        }
    }
    __syncthreads();    // AO complete block-wide; P region dead -> W staging

    // ---- out-projection: wave = (rg, half); Wof staged per-kk in LDS ----
    const int rg = ww & 3, half = ww >> 2;
    const int cb = half * 160;
    f32x4 acc[10] = {};
    for (int kk = 0; kk < 10; ++kk) {
        // stage this kk's 20 frags (20,480 B = 1280 chunks) once per block
        const ushort* wsrc = Wof + (size_t)kk * 10240;
        {
            int c0 = tid, c1 = tid + 512, c2 = tid + 1024;
            *(ushort8*)&W_lds[c0 * 8] = *(const ushort8*)(wsrc + c0 * 8);
            *(ushort8*)&W_lds[c1 * 8] = *(const ushort8*)(wsrc + c1 * 8);
            if (c2 < 1280) *(ushort8*)&W_lds[c2 * 8] = *(const ushort8*)(wsrc + c2 * 8);
        }
        __syncthreads();    // W chunk visible
        bf16x8 a = *(const bf16x8*)&AO_lds[(rg * 16 + c15) * 328 + kk * 32 + khi];
        #pragma unroll
        for (int f = 0; f < 10; ++f) {
            bf16x8 b = *(const bf16x8*)&W_lds[(half * 10 + f) * 512 + l * 8];
            acc[f] = __builtin_amdgcn_mfma_f32_16x16x32_bf16(a, b, acc[f], 0, 0, 0);
        }
        if (kk < 9) __syncthreads();    // reads done before next stage
    }

    // ---- epilogue ----
    const int t0 = blockIdx.x * 64;
    #pragma unroll
    for (int f = 0; f < 10; ++f) {
        int col = cb + f * 16 + c15;
        #pragma unroll
        for (int rr = 0; rr < 4; ++rr)
            out[(size_t)(bt * 4096 + t0 + rg * 16 + rbase + rr) * 320 + col]
                = acc[f][rr] + bias[col];
    }
}

// ---------------------------------------------------------------------------
extern "C" void kernel_launch(void* const* d_in, const int* in_sizes, int n_in,
                              void* d_out, int out_size, void* d_ws, size_t ws_size,
                              hipStream_t stream) {
    (void)in_sizes; (void)n_in; (void)out_size; (void)ws_size;
    const float* hs     = (const float*)d_in[0];   // (8,4096,320)
    const float* ehs    = (const float*)d_in[1];   // (8,77,768)
    const float* mapper = (const float*)d_in[2];   // (3,77,77)
    const float* Wq     = (const float*)d_in[3];   // (320,320)
    const float* Wk     = (const float*)d_in[4];   // (768,320)
    const float* Wv     = (const float*)d_in[5];   // (768,320)
    const float* Wo     = (const float*)d_in[6];   // (320,320)
    const float* bo     = (const float*)d_in[7];   // (320,)
    float* out = (float*)d_out;

    ushort* ws   = (ushort*)d_ws;
    ushort* Wq_t = ws;                             // 320*320
    ushort* Wk_t = Wq_t + 320 * 320;               // 320*768
    ushort* Wv_t = Wk_t + 320 * 768;               // 320*768
    ushort* Wo_t = Wv_t + 320 * 768;               // 320*320
    ushort* Wof  = Wo_t + 320 * 320;               // WF_SZ
    ushort* Qfb  = Wof + WF_SZ;                    // QF_SZ
    ushort* Kfb  = Qfb + QF_SZ;                    // KF_SZ
    ushort* Vfb  = Kfb + KF_SZ;                    // VF_SZ
    ushort* VPfb = Vfb + VF_SZ;                    // VPF_SZ
    ushort* VVt  = VPfb + VPF_SZ;                  // 8*320*80 raw (bt>=5 used)
    float*  part = (float*)(VVt + 8 * 320 * 80);   // 16*640*320 f32 = 13.1 MB

    prep_k<<<1069, 256, 0, stream>>>(Wq, Wk, Wv, Wo, Wq_t, Wk_t, Wv_t, Wo_t,
                                     Kfb, Vfb, VPfb);
    gemm_qkv<<<530, 256, 0, stream>>>(hs, Wq_t, ehs, Wk_t, Wv_t, Wo_t, Qfb, part, Wof);
    kv_reduce<<<dim3(770, 2), 256, 0, stream>>>(part, Kfb, Vfb, VVt);
    vprime_k<<<231, 320, 0, stream>>>(mapper, VVt, VPfb);
    attn_out_k<<<dim3(64, 8), 512, 0, stream>>>(Qfb, Kfb, Vfb, VPfb, Wof, bo, out);
}